// Round 4
// baseline (24.331 us; speedup 1.0000x reference)
//
#include <hip/hip_runtime.h>
#include <stdint.h>

// StringLabelEncoder: for each input row (4x int32 = 128-bit key), find the
// index of the (unique) matching row in the class table [M=50000, 4].
//
// Single-dispatch, class-side hashing: block b hashes ITS 256-class slice
// into a tiny 1024-slot LDS table (1 insert/thread), then probes it with all
// N=4096 query rows (16 independent probes/thread). Exactly one block holds
// each row's class, so out[r] is written exactly once per launch. Probes in
// non-matching blocks hit an EMPTY slot in ~1.15 LDS reads (alpha = 0.25).
//
// vs round 3: eliminates the expensive replicated QUERY-table build
// (32-store clear + 16 dependent CAS chains per thread) in favor of a
// 4-store clear + 1 CAS per thread; the 16 probes are independent and
// pipeline through LDS. Full 128-bit compare stays in LDS (occ word for
// CAS/occupancy + int4 key per slot) -> no global reads in the probe loop.
// CAS race order only permutes slots within a probe chain; chains are
// scanned to EMPTY, so the OUTPUT is deterministic.

#define TS 1024
#define TS_MASK (TS - 1)
#define HASH_EMPTY (-1)
#define KPT 16   // queries per thread: supports N <= 256*KPT = 4096

__global__ __launch_bounds__(256)
void sle_flip_kernel(const int4* __restrict__ x, int N,
                     const int4* __restrict__ cls, int M,
                     int* __restrict__ out) {
    __shared__ int  occ[TS];   // class index or EMPTY (CAS target)
    __shared__ int4 key[TS];   // full 128-bit key per slot

    const int tid = threadIdx.x;
    const int c   = blockIdx.x * 256 + tid;

    // ---- Issue all independent global loads up front. ----
    int4 q = make_int4(0, 0, 0, 0);
    if (c < M) q = cls[c];

    int4 k[KPT];
#pragma unroll
    for (int i = 0; i < KPT; ++i) {
        const int r = tid + i * 256;
        if (r < N) k[i] = x[r];
    }

    // ---- Clear occupancy while loads are in flight. ----
#pragma unroll
    for (int i = 0; i < TS / 256; ++i) occ[tid + i * 256] = HASH_EMPTY;
    __syncthreads();

    // ---- Insert this block's class slice (1 insert/thread). ----
    if (c < M) {
        uint32_t s = (uint32_t)q.x & TS_MASK;
        while (atomicCAS(&occ[s], HASH_EMPTY, c) != HASH_EMPTY)
            s = (s + 1) & TS_MASK;
        key[s] = q;              // visible after the barrier
    }
    __syncthreads();

    // ---- Probe with all N query rows (16 independent probes/thread). ----
#pragma unroll
    for (int i = 0; i < KPT; ++i) {
        const int r = tid + i * 256;
        if (r >= N) break;
        const int4 qq = k[i];
        uint32_t s = (uint32_t)qq.x & TS_MASK;
        while (true) {
            const int v = occ[s];
            if (v == HASH_EMPTY) break;          // class not in this block
            const int4 kk = key[s];
            if (kk.x == qq.x && kk.y == qq.y && kk.z == qq.z && kk.w == qq.w) {
                out[r] = v;                      // unique match: no race
                break;
            }
            s = (s + 1) & TS_MASK;
        }
    }
}

// Fallback for shapes where per-thread query caching would overflow:
// block-per-row scan of the class table.
__global__ void sle_brute_kernel(const int4* __restrict__ x, int N,
                                 const int4* __restrict__ cls, int M,
                                 int* __restrict__ out) {
    __shared__ int found;
    int row = blockIdx.x;
    if (row >= N) return;
    if (threadIdx.x == 0) found = 0;
    __syncthreads();
    int4 q = x[row];
    for (int c = threadIdx.x; c < M; c += blockDim.x) {
        int4 k = cls[c];
        if (k.x == q.x && k.y == q.y && k.z == q.z && k.w == q.w) found = c;
    }
    __syncthreads();
    if (threadIdx.x == 0) out[row] = found;
}

extern "C" void kernel_launch(void* const* d_in, const int* in_sizes, int n_in,
                              void* d_out, int out_size, void* d_ws, size_t ws_size,
                              hipStream_t stream) {
    const int4* x   = (const int4*)d_in[0];   // [N, 4] int32
    const int4* cls = (const int4*)d_in[1];   // [M, 4] int32
    const int N = in_sizes[0] / 4;
    const int M = in_sizes[1] / 4;
    int* out = (int*)d_out;                   // int32 (jax demotes int64 -> int32)

    if (N <= 256 * KPT) {
        int blocks = (M + 255) / 256;
        sle_flip_kernel<<<blocks, 256, 0, stream>>>(x, N, cls, M, out);
    } else {
        sle_brute_kernel<<<N, 256, 0, stream>>>(x, N, cls, M, out);
    }
}

// Round 5
// 18.211 us; speedup vs baseline: 1.3361x; 1.3361x over previous
//
#include <hip/hip_runtime.h>
#include <stdint.h>

// StringLabelEncoder: for each input row (4x int32 = 128-bit key), find the
// index of the (unique) matching row in the class table [M=50000, 4].
//
// Single-dispatch, class-side hashing (round-4 structure) with a
// latency-optimized probe:
//  - block b hashes its 512-class slice into a 4096-slot LDS table
//    (alpha = 0.125), 1 CAS insert/thread
//  - meta[s] = (class_idx, key.x) packed as int2 -> ONE ds_read_b64 per
//    probe step; empty -> done, key.x mismatch -> advance (no 2nd read),
//    key.x match -> verify y/z/w against cls[cidx] (L1-hot slice, ~true
//    matches only; false positive prob ~2^-32 handled by advancing)
//  - probes are BREADTH-FIRST: all 8 queries/thread issue round-0 reads
//    together, then 3 unrolled advance-rounds over the live set, then a
//    (rare, ~1e-3 population) scalar tail. This removes the wave-divergent
//    dependent-LDS-chain serialization that cost round 4 ~7 us.
// Exactly one block holds each row's class, so out[r] is written exactly
// once per launch; CAS race order only permutes slots within a probe chain
// and chains are scanned to EMPTY, so the OUTPUT is deterministic.

#define BLK 512
#define KPT 8            // queries per thread: supports N <= BLK*KPT = 4096
#define TS 4096
#define TS_MASK (TS - 1)
#define HASH_EMPTY (-1)

__global__ __launch_bounds__(BLK)
void sle_flip2_kernel(const int4* __restrict__ x, int N,
                      const int4* __restrict__ cls, int M,
                      int* __restrict__ out) {
    __shared__ int2 meta[TS];   // (class_idx | EMPTY, key.x)

    const int tid = threadIdx.x;
    const int c   = blockIdx.x * BLK + tid;

    // ---- Issue all independent global loads up front. ----
    int4 q = make_int4(0, 0, 0, 0);
    if (c < M) q = cls[c];

    int4 k[KPT];
#pragma unroll
    for (int i = 0; i < KPT; ++i) {
        const int r = tid + i * BLK;
        if (r < N) k[i] = x[r];
    }

    // ---- Clear table while loads are in flight. ----
#pragma unroll
    for (int i = 0; i < TS / BLK; ++i)
        meta[tid + i * BLK] = make_int2(HASH_EMPTY, 0);
    __syncthreads();

    // ---- Insert this block's class slice (1 CAS/thread). ----
    if (c < M) {
        uint32_t s = (uint32_t)q.x & TS_MASK;
        while (atomicCAS(&meta[s].x, HASH_EMPTY, c) != HASH_EMPTY)
            s = (s + 1) & TS_MASK;
        meta[s].y = q.x;          // visible after the barrier
    }
    __syncthreads();

    // ---- Breadth-first probe of all N queries (KPT per thread). ----
    uint32_t s[KPT];
    int2     m[KPT];
    bool     live[KPT];

#pragma unroll
    for (int i = 0; i < KPT; ++i) {
        s[i] = (uint32_t)k[i].x & TS_MASK;
        m[i] = meta[s[i]];                      // independent b64 reads
    }
#pragma unroll
    for (int i = 0; i < KPT; ++i)
        live[i] = (tid + i * BLK < N) && (m[i].x != HASH_EMPTY);

    // One probe step for every live query per round; 3 rounds cover ~99.9%.
#pragma unroll
    for (int d = 0; d < 3; ++d) {
#pragma unroll
        for (int i = 0; i < KPT; ++i) {
            if (!live[i]) continue;
            if (m[i].y == k[i].x) {             // candidate (true match or 2^-32 fp)
                const int  cidx = m[i].x;
                const int4 ck   = cls[cidx];    // this block's slice: L1-hot
                if (ck.y == k[i].y && ck.z == k[i].z && ck.w == k[i].w) {
                    out[tid + i * BLK] = cidx;
                    live[i] = false;
                    continue;
                }
            }
            s[i] = (s[i] + 1) & TS_MASK;
            m[i] = meta[s[i]];
            if (m[i].x == HASH_EMPTY) live[i] = false;
        }
    }

    // Rare tail (~1e-3 of queries still live).
#pragma unroll
    for (int i = 0; i < KPT; ++i) {
        while (live[i]) {
            if (m[i].y == k[i].x) {
                const int  cidx = m[i].x;
                const int4 ck   = cls[cidx];
                if (ck.y == k[i].y && ck.z == k[i].z && ck.w == k[i].w) {
                    out[tid + i * BLK] = cidx;
                    break;
                }
            }
            s[i] = (s[i] + 1) & TS_MASK;
            m[i] = meta[s[i]];
            if (m[i].x == HASH_EMPTY) break;
        }
    }
}

// Fallback for shapes where per-thread query caching would overflow:
// block-per-row scan of the class table.
__global__ void sle_brute_kernel(const int4* __restrict__ x, int N,
                                 const int4* __restrict__ cls, int M,
                                 int* __restrict__ out) {
    __shared__ int found;
    int row = blockIdx.x;
    if (row >= N) return;
    if (threadIdx.x == 0) found = 0;
    __syncthreads();
    int4 q = x[row];
    for (int c = threadIdx.x; c < M; c += blockDim.x) {
        int4 kk = cls[c];
        if (kk.x == q.x && kk.y == q.y && kk.z == q.z && kk.w == q.w) found = c;
    }
    __syncthreads();
    if (threadIdx.x == 0) out[row] = found;
}

extern "C" void kernel_launch(void* const* d_in, const int* in_sizes, int n_in,
                              void* d_out, int out_size, void* d_ws, size_t ws_size,
                              hipStream_t stream) {
    const int4* x   = (const int4*)d_in[0];   // [N, 4] int32
    const int4* cls = (const int4*)d_in[1];   // [M, 4] int32
    const int N = in_sizes[0] / 4;
    const int M = in_sizes[1] / 4;
    int* out = (int*)d_out;                   // int32 (jax demotes int64 -> int32)

    if (N <= BLK * KPT) {
        int blocks = (M + BLK - 1) / BLK;
        sle_flip2_kernel<<<blocks, BLK, 0, stream>>>(x, N, cls, M, out);
    } else {
        sle_brute_kernel<<<N, 256, 0, stream>>>(x, N, cls, M, out);
    }
}

// Round 6
// 9.867 us; speedup vs baseline: 2.4659x; 1.8457x over previous
//
#include <hip/hip_runtime.h>
#include <stdint.h>

// StringLabelEncoder: for each input row (4x int32 = 128-bit key), find the
// index of the (unique) matching row in the class table [M=50000, 4].
//
// Single-dispatch, class-side hashing, latency-minimized probe:
//  - grid = (#512-class slices) x (2 query halves); each block hashes its
//    512 classes into a 4096-slot LDS table (alpha=0.125, 1 CAS/thread)
//    and probes its 2048-query half (KPT=4 per thread).
//  - FULL 128-bit key lives in LDS (occ[] for CAS + key[] int4), so the
//    probe never touches global memory: no cls[] verify load at all.
//  - two-slot lookahead: occ/key for slots s and s+1 are issued for all 4
//    queries in one batch (16 independent LDS reads, single wait), resolved
//    in VALU; a rare tail loop (P ~ alpha^2 = 1.6%) probes further.
//  - only occ[] is cleared (2 int4 stores/thread) while the up-front global
//    loads are in flight.
// Exactly one block (class-slice of row's class x row's half) writes each
// out[r], every replay -> safe under 0xAA poisoning. CAS race order only
// permutes slots within a probe chain; chains are scanned to EMPTY with
// full-key compare, so the OUTPUT is deterministic.

#define BLK 512
#define KPT 4
#define QH  (BLK * KPT)     // 2048 queries per half
#define TS 4096
#define TS_MASK (TS - 1)
#define HASH_EMPTY (-1)

__global__ __launch_bounds__(BLK)
void sle_flip3_kernel(const int4* __restrict__ x, int N,
                      const int4* __restrict__ cls, int M,
                      int* __restrict__ out) {
    __shared__ int  occ[TS];    // class index or EMPTY (CAS target)
    __shared__ int4 key[TS];    // full 128-bit key per slot

    const int tid   = threadIdx.x;
    const int slice = blockIdx.x >> 1;
    const int half  = blockIdx.x & 1;
    const int c     = slice * BLK + tid;
    const int qbase = half * QH;

    // ---- Issue all independent global loads up front. ----
    int4 q = make_int4(0, 0, 0, 0);
    if (c < M) q = cls[c];

    int4 k[KPT];
    int  r[KPT];
#pragma unroll
    for (int i = 0; i < KPT; ++i) {
        r[i] = qbase + tid + i * BLK;
        if (r[i] < N) k[i] = x[r[i]];
    }

    // ---- Clear occupancy (only) while loads are in flight. ----
    {
        int4* o4 = (int4*)occ;
#pragma unroll
        for (int i = 0; i < TS / 4 / BLK; ++i)
            o4[tid + i * BLK] =
                make_int4(HASH_EMPTY, HASH_EMPTY, HASH_EMPTY, HASH_EMPTY);
    }
    __syncthreads();

    // ---- Insert this block's class slice (1 CAS/thread). ----
    if (c < M) {
        uint32_t s = (uint32_t)q.x & TS_MASK;
        while (atomicCAS(&occ[s], HASH_EMPTY, c) != HASH_EMPTY)
            s = (s + 1) & TS_MASK;
        key[s] = q;              // visible after the barrier
    }
    __syncthreads();

    // ---- Probe: slots s and s+1 for all KPT queries, one batch. ----
    uint32_t s0[KPT];
    int      o0[KPT], o1[KPT];
    int4     k0[KPT], k1[KPT];
#pragma unroll
    for (int i = 0; i < KPT; ++i) {
        s0[i] = (uint32_t)k[i].x & TS_MASK;
        const uint32_t s1 = (s0[i] + 1) & TS_MASK;
        o0[i] = occ[s0[i]];
        o1[i] = occ[s1];
        k0[i] = key[s0[i]];      // may be uninit if empty; guarded by occ
        k1[i] = key[s1];
    }

#pragma unroll
    for (int i = 0; i < KPT; ++i) {
        if (r[i] >= N) continue;
        const int4 qq = k[i];
        if (o0[i] == HASH_EMPTY) continue;   // chain empty: class not here
        if (k0[i].x == qq.x && k0[i].y == qq.y &&
            k0[i].z == qq.z && k0[i].w == qq.w) {
            out[r[i]] = o0[i];
            continue;
        }
        if (o1[i] == HASH_EMPTY) continue;
        if (k1[i].x == qq.x && k1[i].y == qq.y &&
            k1[i].z == qq.z && k1[i].w == qq.w) {
            out[r[i]] = o1[i];
            continue;
        }
        // Rare tail (~alpha^2 of queries).
        uint32_t s = (s0[i] + 2) & TS_MASK;
        while (true) {
            const int v = occ[s];
            if (v == HASH_EMPTY) break;
            const int4 kk = key[s];
            if (kk.x == qq.x && kk.y == qq.y &&
                kk.z == qq.z && kk.w == qq.w) {
                out[r[i]] = v;
                break;
            }
            s = (s + 1) & TS_MASK;
        }
    }
}

// Fallback for shapes the LDS scheme doesn't cover: block-per-row scan.
__global__ void sle_brute_kernel(const int4* __restrict__ x, int N,
                                 const int4* __restrict__ cls, int M,
                                 int* __restrict__ out) {
    __shared__ int found;
    int row = blockIdx.x;
    if (row >= N) return;
    if (threadIdx.x == 0) found = 0;
    __syncthreads();
    int4 qv = x[row];
    for (int c = threadIdx.x; c < M; c += blockDim.x) {
        int4 kk = cls[c];
        if (kk.x == qv.x && kk.y == qv.y && kk.z == qv.z && kk.w == qv.w)
            found = c;
    }
    __syncthreads();
    if (threadIdx.x == 0) out[row] = found;
}

extern "C" void kernel_launch(void* const* d_in, const int* in_sizes, int n_in,
                              void* d_out, int out_size, void* d_ws, size_t ws_size,
                              hipStream_t stream) {
    const int4* x   = (const int4*)d_in[0];   // [N, 4] int32
    const int4* cls = (const int4*)d_in[1];   // [M, 4] int32
    const int N = in_sizes[0] / 4;
    const int M = in_sizes[1] / 4;
    int* out = (int*)d_out;                   // int32 (jax demotes int64 -> int32)

    if (N <= 2 * QH) {
        const int nslices = (M + BLK - 1) / BLK;
        sle_flip3_kernel<<<nslices * 2, BLK, 0, stream>>>(x, N, cls, M, out);
    } else {
        sle_brute_kernel<<<N, 256, 0, stream>>>(x, N, cls, M, out);
    }
}

// Round 7
// 9.666 us; speedup vs baseline: 2.5172x; 1.0208x over previous
//
#include <hip/hip_runtime.h>
#include <stdint.h>

// StringLabelEncoder: for each input row (4x int32 = 128-bit key), find the
// index of the (unique) matching row in the class table [M=50000, 4].
//
// Single-dispatch, class-side hashing, meta-fastpath probe:
//  - grid = (#512-class slices) x (2 query halves); block hashes its 512
//    classes into a 4096-slot LDS table (alpha=0.125, 1 CAS/thread), then
//    probes its 2048-query half (KPT=4/thread).
//  - meta[s] = (class_idx | EMPTY, key.x) as int2 -> ONE ds_read_b64 per
//    slot; vkey[s] = (key.y, key.z, key.w) is read ONLY when key.x matches
//    (~1% of queries, 2^-32 false-positive rate otherwise advances).
//  - probe is fully batched: {meta[s0], meta[s1]} for all 4 queries in one
//    wait; masked vkey verifies in a second wait; rare tail loop (~alpha^2).
// Exactly one block (row's class-slice x row's half) writes each out[r]
// every replay -> safe under 0xAA poisoning. CAS race order only permutes
// slots within a probe chain; chains are scanned to EMPTY with full 128-bit
// compare, so the OUTPUT is deterministic.

#define BLK 512
#define KPT 4
#define QH  (BLK * KPT)     // 2048 queries per half
#define TS 4096
#define TS_MASK (TS - 1)
#define HASH_EMPTY (-1)

__global__ __launch_bounds__(BLK)
void sle_flip4_kernel(const int4* __restrict__ x, int N,
                      const int4* __restrict__ cls, int M,
                      int* __restrict__ out) {
    __shared__ int2 meta[TS];   // (class_idx | EMPTY, key.x)
    __shared__ int4 vkey[TS];   // (key.y, key.z, key.w, unused)

    const int tid   = threadIdx.x;
    const int slice = blockIdx.x >> 1;
    const int half  = blockIdx.x & 1;
    const int c     = slice * BLK + tid;
    const int qbase = half * QH;

    // ---- Issue all independent global loads up front. ----
    int4 q = make_int4(0, 0, 0, 0);
    if (c < M) q = cls[c];

    int4 k[KPT];
    int  r[KPT];
#pragma unroll
    for (int i = 0; i < KPT; ++i) {
        r[i] = qbase + tid + i * BLK;
        if (r[i] < N) k[i] = x[r[i]];
    }

    // ---- Clear meta while loads are in flight (b128 stores, 2 slots ea). ----
    {
        int4* m4 = (int4*)meta;
#pragma unroll
        for (int i = 0; i < (TS * 8) / 16 / BLK; ++i)
            m4[tid + i * BLK] = make_int4(HASH_EMPTY, 0, HASH_EMPTY, 0);
    }
    __syncthreads();

    // ---- Insert this block's class slice (1 CAS/thread). ----
    if (c < M) {
        uint32_t s = (uint32_t)q.x & TS_MASK;
        while (atomicCAS(&meta[s].x, HASH_EMPTY, c) != HASH_EMPTY)
            s = (s + 1) & TS_MASK;
        meta[s].y = q.x;
        vkey[s] = make_int4(q.y, q.z, q.w, 0);
    }
    __syncthreads();

    // ---- Batch 1: meta for slots s0, s0+1 of all KPT queries. ----
    uint32_t s0[KPT];
    int2     m0[KPT], m1[KPT];
#pragma unroll
    for (int i = 0; i < KPT; ++i) {
        s0[i] = (uint32_t)k[i].x & TS_MASK;
        m0[i] = meta[s0[i]];
        m1[i] = meta[(s0[i] + 1) & TS_MASK];
    }

    // ---- Batch 2: masked vkey verifies (rare: key.x already matched). ----
    int4 v0[KPT], v1[KPT];
    bool n0[KPT], n1[KPT];
#pragma unroll
    for (int i = 0; i < KPT; ++i) {
        const bool ok = (r[i] < N);
        n0[i] = ok && m0[i].x != HASH_EMPTY && m0[i].y == k[i].x;
        n1[i] = ok && m0[i].x != HASH_EMPTY && m1[i].x != HASH_EMPTY &&
                m1[i].y == k[i].x;
        if (n0[i]) v0[i] = vkey[s0[i]];
        if (n1[i]) v1[i] = vkey[(s0[i] + 1) & TS_MASK];
    }

    // ---- Resolve (pure VALU; tail loop ~alpha^2 of queries). ----
#pragma unroll
    for (int i = 0; i < KPT; ++i) {
        if (r[i] >= N) continue;
        const int4 qq = k[i];
        if (m0[i].x == HASH_EMPTY) continue;        // chain empty
        if (n0[i] && v0[i].x == qq.y && v0[i].y == qq.z && v0[i].z == qq.w) {
            out[r[i]] = m0[i].x;
            continue;
        }
        if (m1[i].x == HASH_EMPTY) continue;
        if (n1[i] && v1[i].x == qq.y && v1[i].y == qq.z && v1[i].z == qq.w) {
            out[r[i]] = m1[i].x;
            continue;
        }
        // Tail: probe from s0+2 until EMPTY.
        uint32_t s = (s0[i] + 2) & TS_MASK;
        while (true) {
            const int2 m = meta[s];
            if (m.x == HASH_EMPTY) break;
            if (m.y == qq.x) {
                const int4 v = vkey[s];
                if (v.x == qq.y && v.y == qq.z && v.z == qq.w) {
                    out[r[i]] = m.x;
                    break;
                }
            }
            s = (s + 1) & TS_MASK;
        }
    }
}

// Fallback for shapes the LDS scheme doesn't cover: block-per-row scan.
__global__ void sle_brute_kernel(const int4* __restrict__ x, int N,
                                 const int4* __restrict__ cls, int M,
                                 int* __restrict__ out) {
    __shared__ int found;
    int row = blockIdx.x;
    if (row >= N) return;
    if (threadIdx.x == 0) found = 0;
    __syncthreads();
    int4 qv = x[row];
    for (int c = threadIdx.x; c < M; c += blockDim.x) {
        int4 kk = cls[c];
        if (kk.x == qv.x && kk.y == qv.y && kk.z == qv.z && kk.w == qv.w)
            found = c;
    }
    __syncthreads();
    if (threadIdx.x == 0) out[row] = found;
}

extern "C" void kernel_launch(void* const* d_in, const int* in_sizes, int n_in,
                              void* d_out, int out_size, void* d_ws, size_t ws_size,
                              hipStream_t stream) {
    const int4* x   = (const int4*)d_in[0];   // [N, 4] int32
    const int4* cls = (const int4*)d_in[1];   // [M, 4] int32
    const int N = in_sizes[0] / 4;
    const int M = in_sizes[1] / 4;
    int* out = (int*)d_out;                   // int32 (jax demotes int64 -> int32)

    if (N <= 2 * QH) {
        const int nslices = (M + BLK - 1) / BLK;
        sle_flip4_kernel<<<nslices * 2, BLK, 0, stream>>>(x, N, cls, M, out);
    } else {
        sle_brute_kernel<<<N, 256, 0, stream>>>(x, N, cls, M, out);
    }
}